// Round 6
// baseline (115.641 us; speedup 1.0000x reference)
//
#include <hip/hip_runtime.h>

// B=2, C=3, H=W=1024, fp32. History: R12 56.1us; R13 float4-pack regressed;
// R14/R15 53.5us (conflicts pinned 1.478e7 = live-load cost); R16 45.3us:
// 32x8 tile + TSTR=48 (row bank-shift 16) cut conflicts to 1.091e7 and FETCH
// to 60.5MB. Remaining: VALU 65% (top), LDS-unit ~50%, HBM 24%.
// R17: packed-fp32 march. MI355X fp32 peak requires v_pk_{fma,mul,add}_f32
// (2 lanes/instr, full rate); our A=+v0 / B=-v0 chains are an idle 2-way
// SIMD axis. Interior march rewritten on float ext_vector(2), lane={A,B}:
// pk_mul+pk_add (contract off) on trajectory path == scalar mul/add per
// lane; fma on color path == fmaf. Int addressing + LDS reads stay scalar
// per chain (identical access stream => conflicts must stay ~1.09e7).
// Border blocks (6%) keep R16 scalar code verbatim. absmax must remain
// exactly 0.00390625.
constexpr int Bb = 2, Cc = 3, Hh = 1024, Ww = 1024;
constexpr int HWp = Hh * Ww;
constexpr int TSX = 32, TSY = 8;        // tile 32x8, 256 threads
constexpr int HALO = 6;                 // >= max drift 4.5 + margin
constexpr int TDX = TSX + 2 * HALO;     // 44
constexpr int TDY = TSY + 2 * HALO;     // 20
constexpr int TSTR = 48;                // row stride == 16 mod 32: bank comb

typedef float v2f __attribute__((ext_vector_type(2)));

struct Corn { int o00, o01, o10, o11; float wx, wy, omx, omy; };
struct CornP { int oA, oB; v2f wx, wy, omx, omy; };

// ---- packed interior corner: per-lane arithmetic identical to scalar
__device__ __forceinline__ CornP mkcornp(v2f px, v2f py, int ox, int oy) {
#pragma clang fp contract(off)
    v2f fx = px - 0.5f;
    v2f fy = py - 0.5f;
    v2f fx0 = __builtin_elementwise_floor(fx);
    v2f fy0 = __builtin_elementwise_floor(fy);
    CornP c;
    c.wx = fx - fx0;  c.wy = fy - fy0;
    c.omx = 1.0f - c.wx;  c.omy = 1.0f - c.wy;
    c.oA = ((int)fy0.x - oy) * TSTR + ((int)fx0.x - ox);
    c.oB = ((int)fy0.y - oy) * TSTR + ((int)fx0.y - ox);
    return c;
}

// ---- scalar border corner: full clamp logic, identical to R16
__device__ __forceinline__ Corn mkcorn_bor(float px, float py, int ox, int oy) {
#pragma clang fp contract(off)
    float fx = px - 0.5f;
    float fy = py - 0.5f;
    float fx0 = floorf(fx), fy0 = floorf(fy);
    Corn c;
    c.wx = fx - fx0;  c.wy = fy - fy0;
    c.omx = 1.0f - c.wx;  c.omy = 1.0f - c.wy;
    int x0 = (int)fx0, y0 = (int)fy0;
    int x0i = min(max(x0, 0), Ww - 1);
    int x1i = min(x0i + 1, Ww - 1);
    int y0i = min(max(y0, 0), Hh - 1);
    int y1i = min(y0i + 1, Hh - 1);
    int lx0 = x0i - ox, lx1 = x1i - ox;
    int ly0 = y0i - oy, ly1 = y1i - oy;
    c.o00 = ly0 * TSTR + lx0;  c.o01 = ly0 * TSTR + lx1;
    c.o10 = ly1 * TSTR + lx0;  c.o11 = ly1 * TSTR + lx1;
    return c;
}

template <bool BORDER>
__device__ __forceinline__ void run_tile(
    const float* __restrict__ x, const float* __restrict__ tg,
    const float* __restrict__ sg, float* __restrict__ out,
    float (&lds)[5][TDY * TSTR])
{
#pragma clang fp contract(off)
    const int tx0 = blockIdx.x * TSX, ty0 = blockIdx.y * TSY;
    const int b = blockIdx.z;
    const int tid = threadIdx.x;          // 0..255

    const float* xp  = x  + (size_t)b * Cc * HWp;
    const float* txp = tg + (size_t)b * 2 * HWp;
    const float* planes[5] = { xp, xp + HWp, xp + 2 * HWp, txp, txp + HWp };
    const int ox = tx0 - HALO, oy = ty0 - HALO;

    // ---- uniform per-block kernel weights (overlap staging latency)
    float sig = sg[b];
    float half_width = 2.0f * sig;
    float two_sigma2 = (2.0f * sig) * sig;
    const float stepf = (float)(1.0 / 0.3333);
    float kv[4];
#pragma unroll
    for (int it = 0; it < 4; ++it) {
        float r = ((float)it + 1.0f) * stepf;
        float k = expf(-(r * r) / two_sigma2);
        kv[it] = (r < half_width) ? k : 0.0f;
    }
    const float k0 = kv[0], k1 = kv[1], k2 = kv[2], k3 = kv[3];
    // ks-nonzero is a prefix (exp never 0; r<half_width monotone shut-off).
    const int nlive = __builtin_amdgcn_readfirstlane(
        (k0 != 0.0f) + (k1 != 0.0f) + (k2 != 0.0f) + (k3 != 0.0f));

    // ---- stage 20x44 x 5 planes into LDS
    if (!BORDER) {
        // interior: ox is even (tx0 = 32k, HALO = 6) => float2 aligned
        for (int e = tid; e < TDY * (TDX / 2); e += 256) {
            int r = e / (TDX / 2);
            int c2 = e - r * (TDX / 2);
            int g = (oy + r) * Ww + ox + 2 * c2;
            int d = r * TSTR + 2 * c2;
#pragma unroll
            for (int pl = 0; pl < 5; ++pl) {
                float2 v = *reinterpret_cast<const float2*>(planes[pl] + g);
                *reinterpret_cast<float2*>(&lds[pl][d]) = v;
            }
        }
    } else {
        for (int e = tid; e < TDY * TDX; e += 256) {
            int r = e / TDX, cc = e - r * TDX;
            int gy = min(max(oy + r, 0), Hh - 1);
            int gx = min(max(ox + cc, 0), Ww - 1);
            int g = gy * Ww + gx;
#pragma unroll
            for (int pl = 0; pl < 5; ++pl)
                lds[pl][r * TSTR + cc] = planes[pl][g];
        }
    }
    __syncthreads();

    // ---- per-pixel march, positions in PIXEL units (exact x1024 rescale)
    const int lx = tid & (TSX - 1), ly = tid >> 5;   // 32x8
    const int j = tx0 + lx, i = ty0 + ly;
    const int ctr = (HALO + ly) * TSTR + (HALO + lx);

    const float psx = (float)j + 0.5f;
    const float psy = (float)i + 0.5f;

    const float v0x = lds[3][ctr];
    const float v0y = lds[4][ctr];

    const int pix = i * Ww + j;
    float* op = out + (size_t)b * Cc * HWp;
    const float xc0 = lds[0][ctr], xc1 = lds[1][ctr], xc2 = lds[2][ctr];

    if constexpr (!BORDER) {
        // ================= packed interior march: lane = {A,B} =========
        v2f vx = { v0x, -v0x }, vy = { v0y, -v0y };
        v2f px = psx + vx, py = psy + vy;   // psx - v0x == psx + (-v0x) exact
        v2f a0 = {0.f, 0.f}, a1 = {0.f, 0.f}, a2 = {0.f, 0.f};
        v2f asv = {0.f, 0.f};

#define GATHER(PL, Q00, Q01, Q10, Q11, C)                                   \
    v2f Q00 = { lds[PL][C.oA],            lds[PL][C.oB] };                  \
    v2f Q01 = { lds[PL][C.oA + 1],        lds[PL][C.oB + 1] };              \
    v2f Q10 = { lds[PL][C.oA + TSTR],     lds[PL][C.oB + TSTR] };           \
    v2f Q11 = { lds[PL][C.oA + TSTR + 1], lds[PL][C.oB + TSTR + 1] };

#define COLORP(C, K) do {                                                   \
    v2f w00 = C.omx * C.omy, w01 = C.wx * C.omy;                            \
    v2f w10 = C.omx * C.wy,  w11 = C.wx * C.wy;                             \
    v2f kk = { (K), (K) };                                                  \
    GATHER(0, p00, p01, p10, p11, C)                                        \
    v2f s0 = __builtin_elementwise_fma(w01, p01, w00 * p00);                \
    s0 = __builtin_elementwise_fma(w10, p10, s0);                           \
    s0 = __builtin_elementwise_fma(w11, p11, s0);                           \
    a0 = __builtin_elementwise_fma(s0, kk, a0);                             \
    GATHER(1, q00, q01, q10, q11, C)                                        \
    v2f s1 = __builtin_elementwise_fma(w01, q01, w00 * q00);                \
    s1 = __builtin_elementwise_fma(w10, q10, s1);                           \
    s1 = __builtin_elementwise_fma(w11, q11, s1);                           \
    a1 = __builtin_elementwise_fma(s1, kk, a1);                             \
    GATHER(2, r00, r01, r10, r11, C)                                        \
    v2f s2 = __builtin_elementwise_fma(w01, r01, w00 * r00);                \
    s2 = __builtin_elementwise_fma(w10, r10, s2);                           \
    s2 = __builtin_elementwise_fma(w11, r11, s2);                           \
    a2 = __builtin_elementwise_fma(s2, kk, a2);                             \
    asv += kk;                                                              \
} while (0)

        // trajectory: pk_mul + pk_add under contract(off) == scalar mul/add
#define ADVP(C) do {                                                        \
    GATHER(3, x00, x01, x10, x11, C)                                        \
    GATHER(4, y00, y01, y10, y11, C)                                        \
    v2f xt = x00 * C.omx + x01 * C.wx;                                      \
    v2f xb = x10 * C.omx + x11 * C.wx;                                      \
    v2f tfx = xt * C.omy + xb * C.wy;                                       \
    v2f yt = y00 * C.omx + y01 * C.wx;                                      \
    v2f yb = y10 * C.omx + y11 * C.wx;                                      \
    v2f tfy = yt * C.omy + yb * C.wy;                                       \
    v2f vt = vx * tfx + vy * tfy;                                           \
    if (vt.x < 0.0f) { tfx.x = -tfx.x; tfy.x = -tfy.x; }                    \
    if (vt.y < 0.0f) { tfx.y = -tfx.y; tfy.y = -tfy.y; }                    \
    px += tfx;  py += tfy;                                                  \
    vx = tfx;   vy = tfy;                                                   \
} while (0)

        if (nlive >= 1) {
            CornP c0 = mkcornp(px, py, ox, oy);
            COLORP(c0, k0);
            if (nlive >= 2) {
                ADVP(c0);
                CornP c1 = mkcornp(px, py, ox, oy);
                COLORP(c1, k1);
                if (nlive >= 3) {
                    ADVP(c1);
                    CornP c2 = mkcornp(px, py, ox, oy);
                    COLORP(c2, k2);
                    if (nlive >= 4) {
                        ADVP(c2);
                        CornP c3 = mkcornp(px, py, ox, oy);
                        COLORP(c3, k3);
                    }
                }
            }
        }
#undef GATHER
#undef COLORP
#undef ADVP

        float denom = (1.0f + asv.x) + asv.y;
        op[pix]           = ((xc0 + a0.x) + a0.y) / denom;
        op[pix + HWp]     = ((xc1 + a1.x) + a1.y) / denom;
        op[pix + 2 * HWp] = ((xc2 + a2.x) + a2.y) / denom;
    } else {
        // ================= scalar border march (R16 verbatim) ==========
        float pxA = psx + v0x, pyA = psy + v0y, vxA = v0x, vyA = v0y;
        float pxB = psx - v0x, pyB = psy - v0y, vxB = -v0x, vyB = -v0y;
        float aA0 = 0.f, aA1 = 0.f, aA2 = 0.f, asA = 0.f;
        float aB0 = 0.f, aB1 = 0.f, aB2 = 0.f, asB = 0.f;

#define MKC(C, PX, PY)  Corn C = mkcorn_bor(PX, PY, ox, oy)

#define COLORSTEP(C, PX, PY, KW, A0, A1, A2, AS) do {                       \
    float w_ = (KW);                                                        \
    bool inb_ = ((PX) >= 0.0f) && ((PX) < 1024.0f) &&                       \
                ((PY) >= 0.0f) && ((PY) < 1024.0f);                         \
    w_ = inb_ ? w_ : 0.0f;                                                  \
    float w00_ = C.omx * C.omy, w01_ = C.wx * C.omy;                        \
    float w10_ = C.omx * C.wy,  w11_ = C.wx * C.wy;                         \
    float s0_ = fmaf(w01_, lds[0][C.o01], w00_ * lds[0][C.o00]);            \
    s0_ = fmaf(w10_, lds[0][C.o10], s0_);                                   \
    s0_ = fmaf(w11_, lds[0][C.o11], s0_);                                   \
    A0 = fmaf(s0_, w_, A0);                                                 \
    float s1_ = fmaf(w01_, lds[1][C.o01], w00_ * lds[1][C.o00]);            \
    s1_ = fmaf(w10_, lds[1][C.o10], s1_);                                   \
    s1_ = fmaf(w11_, lds[1][C.o11], s1_);                                   \
    A1 = fmaf(s1_, w_, A1);                                                 \
    float s2_ = fmaf(w01_, lds[2][C.o01], w00_ * lds[2][C.o00]);            \
    s2_ = fmaf(w10_, lds[2][C.o10], s2_);                                   \
    s2_ = fmaf(w11_, lds[2][C.o11], s2_);                                   \
    A2 = fmaf(s2_, w_, A2);                                                 \
    AS += w_;                                                               \
} while (0)

#define ADVSTEP(C, PX, PY, VX, VY) do {                                     \
    float x00_ = lds[3][C.o00], x01_ = lds[3][C.o01];                       \
    float x10_ = lds[3][C.o10], x11_ = lds[3][C.o11];                       \
    float y00_ = lds[4][C.o00], y01_ = lds[4][C.o01];                       \
    float y10_ = lds[4][C.o10], y11_ = lds[4][C.o11];                       \
    float xt_ = x00_ * C.omx + x01_ * C.wx;                                 \
    float xb_ = x10_ * C.omx + x11_ * C.wx;                                 \
    float tfx_ = xt_ * C.omy + xb_ * C.wy;                                  \
    float yt_ = y00_ * C.omx + y01_ * C.wx;                                 \
    float yb_ = y10_ * C.omx + y11_ * C.wx;                                 \
    float tfy_ = yt_ * C.omy + yb_ * C.wy;                                  \
    float vt_ = ((VX) * tfx_) + ((VY) * tfy_);                              \
    if (vt_ < 0.0f) { tfx_ = -tfx_; tfy_ = -tfy_; }                         \
    PX = (PX) + tfx_;  PY = (PY) + tfy_;                                    \
    VX = tfx_;  VY = tfy_;                                                  \
} while (0)

        if (nlive >= 1) {
            MKC(cA0, pxA, pyA);  MKC(cB0, pxB, pyB);
            COLORSTEP(cA0, pxA, pyA, k0, aA0, aA1, aA2, asA);
            COLORSTEP(cB0, pxB, pyB, k0, aB0, aB1, aB2, asB);
            if (nlive >= 2) {
                ADVSTEP(cA0, pxA, pyA, vxA, vyA);
                ADVSTEP(cB0, pxB, pyB, vxB, vyB);
                MKC(cA1, pxA, pyA);  MKC(cB1, pxB, pyB);
                COLORSTEP(cA1, pxA, pyA, k1, aA0, aA1, aA2, asA);
                COLORSTEP(cB1, pxB, pyB, k1, aB0, aB1, aB2, asB);
                if (nlive >= 3) {
                    ADVSTEP(cA1, pxA, pyA, vxA, vyA);
                    ADVSTEP(cB1, pxB, pyB, vxB, vyB);
                    MKC(cA2, pxA, pyA);  MKC(cB2, pxB, pyB);
                    COLORSTEP(cA2, pxA, pyA, k2, aA0, aA1, aA2, asA);
                    COLORSTEP(cB2, pxB, pyB, k2, aB0, aB1, aB2, asB);
                    if (nlive >= 4) {
                        ADVSTEP(cA2, pxA, pyA, vxA, vyA);
                        ADVSTEP(cB2, pxB, pyB, vxB, vyB);
                        MKC(cA3, pxA, pyA);  MKC(cB3, pxB, pyB);
                        COLORSTEP(cA3, pxA, pyA, k3, aA0, aA1, aA2, asA);
                        COLORSTEP(cB3, pxB, pyB, k3, aB0, aB1, aB2, asB);
                    }
                }
            }
        }
#undef MKC
#undef COLORSTEP
#undef ADVSTEP

        float denom = (1.0f + asA) + asB;
        op[pix]           = ((xc0 + aA0) + aB0) / denom;
        op[pix + HWp]     = ((xc1 + aA1) + aB1) / denom;
        op[pix + 2 * HWp] = ((xc2 + aA2) + aB2) / denom;
    }
}

__global__ __launch_bounds__(256, 8) void flow_smooth_kernel(
    const float* __restrict__ x,
    const float* __restrict__ tg,
    const float* __restrict__ sg,
    float* __restrict__ out)
{
    __shared__ float lds[5][TDY * TSTR];   // 5 x 960 x 4B = 19.2 KB
    const bool border = (blockIdx.x == 0) || (blockIdx.x == gridDim.x - 1) ||
                        (blockIdx.y == 0) || (blockIdx.y == gridDim.y - 1);
    if (border) run_tile<true >(x, tg, sg, out, lds);
    else        run_tile<false>(x, tg, sg, out, lds);
}

extern "C" void kernel_launch(void* const* d_in, const int* in_sizes, int n_in,
                              void* d_out, int out_size, void* d_ws, size_t ws_size,
                              hipStream_t stream) {
    const float* x = nullptr; const float* tg = nullptr; const float* sg = nullptr;
    for (int t = 0; t < n_in; ++t) {
        if (in_sizes[t] == Bb * Cc * HWp)      x  = (const float*)d_in[t];
        else if (in_sizes[t] == Bb * 2 * HWp)  tg = (const float*)d_in[t];
        else                                   sg = (const float*)d_in[t];
    }
    float* out = (float*)d_out;

    dim3 block(256, 1, 1);
    dim3 grid(Ww / TSX, Hh / TSY, Bb);   // 32 x 128 x 2 = 8192 blocks
    flow_smooth_kernel<<<grid, block, 0, stream>>>(x, tg, sg, out);
}

// Round 7
// 115.573 us; speedup vs baseline: 1.0006x; 1.0006x over previous
//
#include <hip/hip_runtime.h>

// B=2, C=3, H=W=1024, fp32. History: R12 56.1us; R13 float4-record-pack
// regressed (conflicts +21%/word); R16 45.3us = 32x8 tile + TSTR=48 bank-comb
// (conflicts 1.478e7 -> 1.091e7, FETCH 60.5MB); R17 v2f packed march
// REGRESSED 53.9us: VALU busy-cycles unchanged (clang scalarized) and packing
// COUPLED the A/B dep chains (every op waits on max of both loads) -> stalls.
// R18: revert to R16 march verbatim; attack staging + per-block overhead.
//  - 32x16 tile @ 512 threads, 2px/thread-column ratio via bigger tile (still
//    1 px/thread): halo amortization 17.2 -> 13.1 staged words/px.
//  - staged window starts at ox4 = tx0-8 (= 0 mod 4) and spans 48 = TSTR
//    cols: float4 global loads + b128 LDS writes, ~5x fewer staging instrs.
//  - 4096 blocks (half): expf chain / barrier / launch amortized over 2x px.
//  - LDS 5x28x48x4 = 26.9KB -> 4 blocks/CU (wave-capped 32 waves, same as
//    R16). March gather stream per px identical => conflicts stay ~1.09e7.
// March/clamp arithmetic untouched => absmax must remain exactly 0.00390625.
constexpr int Bb = 2, Cc = 3, Hh = 1024, Ww = 1024;
constexpr int HWp = Hh * Ww;
constexpr int TSX = 32, TSY = 16;       // tile 32x16, 512 threads
constexpr int HALOX = 8;                // staged x-halo (>=4.5 drift; 4-align)
constexpr int HALOY = 6;                // staged y-halo
constexpr int TDX = TSX + 2 * HALOX;    // 48 == TSTR (no x pad waste)
constexpr int TDY = TSY + 2 * HALOY;    // 28
constexpr int TSTR = 48;                // row stride == 16 mod 32: bank comb

struct Corn { int o00, o01, o10, o11; float wx, wy, omx, omy; };

// Interior: pixel-space positions, never clamps (drift bound |dp|<=4.5px).
__device__ __forceinline__ Corn mkcorn_int(float px, float py, int ox, int oy) {
#pragma clang fp contract(off)
    float fx = px - 0.5f;
    float fy = py - 0.5f;
    float fx0 = floorf(fx), fy0 = floorf(fy);
    Corn c;
    c.wx = fx - fx0;  c.wy = fy - fy0;
    c.omx = 1.0f - c.wx;  c.omy = 1.0f - c.wy;
    int o = ((int)fy0 - oy) * TSTR + ((int)fx0 - ox);
    c.o00 = o;        c.o01 = o + 1;          // read2-mergeable pairs
    c.o10 = o + TSTR; c.o11 = o + TSTR + 1;
    return c;
}

// Border: full clamp logic, arithmetic identical to R12/R16.
__device__ __forceinline__ Corn mkcorn_bor(float px, float py, int ox, int oy) {
#pragma clang fp contract(off)
    float fx = px - 0.5f;
    float fy = py - 0.5f;
    float fx0 = floorf(fx), fy0 = floorf(fy);
    Corn c;
    c.wx = fx - fx0;  c.wy = fy - fy0;
    c.omx = 1.0f - c.wx;  c.omy = 1.0f - c.wy;
    int x0 = (int)fx0, y0 = (int)fy0;
    int x0i = min(max(x0, 0), Ww - 1);
    int x1i = min(x0i + 1, Ww - 1);
    int y0i = min(max(y0, 0), Hh - 1);
    int y1i = min(y0i + 1, Hh - 1);
    int lx0 = x0i - ox, lx1 = x1i - ox;
    int ly0 = y0i - oy, ly1 = y1i - oy;
    c.o00 = ly0 * TSTR + lx0;  c.o01 = ly0 * TSTR + lx1;
    c.o10 = ly1 * TSTR + lx0;  c.o11 = ly1 * TSTR + lx1;
    return c;
}

template <bool BORDER>
__device__ __forceinline__ void run_tile(
    const float* __restrict__ x, const float* __restrict__ tg,
    const float* __restrict__ sg, float* __restrict__ out,
    float (&lds)[5][TDY * TSTR])
{
#pragma clang fp contract(off)
    const int tx0 = blockIdx.x * TSX, ty0 = blockIdx.y * TSY;
    const int b = blockIdx.z;
    const int tid = threadIdx.x;          // 0..511

    const float* xp  = x  + (size_t)b * Cc * HWp;
    const float* txp = tg + (size_t)b * 2 * HWp;
    const float* planes[5] = { xp, xp + HWp, xp + 2 * HWp, txp, txp + HWp };
    const int ox = tx0 - HALOX, oy = ty0 - HALOY;   // ox == 0 mod 4

    // ---- uniform per-block kernel weights (overlap staging latency)
    float sig = sg[b];
    float half_width = 2.0f * sig;
    float two_sigma2 = (2.0f * sig) * sig;
    const float stepf = (float)(1.0 / 0.3333);
    float kv[4];
#pragma unroll
    for (int it = 0; it < 4; ++it) {
        float r = ((float)it + 1.0f) * stepf;
        float k = expf(-(r * r) / two_sigma2);
        kv[it] = (r < half_width) ? k : 0.0f;
    }
    const float k0 = kv[0], k1 = kv[1], k2 = kv[2], k3 = kv[3];
    // ks-nonzero is a prefix (exp never 0; r<half_width monotone shut-off).
    const int nlive = __builtin_amdgcn_readfirstlane(
        (k0 != 0.0f) + (k1 != 0.0f) + (k2 != 0.0f) + (k3 != 0.0f));

    // ---- stage 28x48 x 5 planes into LDS
    if (!BORDER) {
        // interior: ox = 0 mod 4 => float4 loads, b128 LDS writes.
        // 5 planes x 28 rows x 12 float4 = 1680 vec4s / 512 threads.
        for (int e = tid; e < 5 * TDY * (TDX / 4); e += 512) {
            int row = e / (TDX / 4);            // 0..139 (pl*28 + r)
            int c4  = e - row * (TDX / 4);      // 0..11
            int pl  = row / TDY;
            int r   = row - pl * TDY;
            int g = (oy + r) * Ww + ox + 4 * c4;
            float4 v = *reinterpret_cast<const float4*>(planes[pl] + g);
            *reinterpret_cast<float4*>(&lds[pl][r * TSTR + 4 * c4]) = v;
        }
    } else {
        for (int e = tid; e < TDY * TDX; e += 512) {
            int r = e / TDX, cc = e - r * TDX;
            int gy = min(max(oy + r, 0), Hh - 1);
            int gx = min(max(ox + cc, 0), Ww - 1);
            int g = gy * Ww + gx;
#pragma unroll
            for (int pl = 0; pl < 5; ++pl)
                lds[pl][r * TSTR + cc] = planes[pl][g];
        }
    }
    __syncthreads();

    // ---- per-pixel march, positions in PIXEL units (exact x1024 rescale)
    const int lx = tid & (TSX - 1), ly = tid >> 5;   // 32x16
    const int j = tx0 + lx, i = ty0 + ly;
    const int ctr = (HALOY + ly) * TSTR + (HALOX + lx);

    const float psx = (float)j + 0.5f;
    const float psy = (float)i + 0.5f;

    const float v0x = lds[3][ctr];
    const float v0y = lds[4][ctr];

    // two independent chains: A = +v0, B = -v0 (manually interleaved)
    float pxA = psx + v0x, pyA = psy + v0y, vxA = v0x, vyA = v0y;
    float pxB = psx - v0x, pyB = psy - v0y, vxB = -v0x, vyB = -v0y;
    float aA0 = 0.f, aA1 = 0.f, aA2 = 0.f, asA = 0.f;
    float aB0 = 0.f, aB1 = 0.f, aB2 = 0.f, asB = 0.f;

#define MKC(C, PX, PY)                                                      \
    Corn C = BORDER ? mkcorn_bor(PX, PY, ox, oy)                            \
                    : mkcorn_int(PX, PY, ox, oy)

#define COLORSTEP(C, PX, PY, KW, A0, A1, A2, AS) do {                       \
    float w_ = (KW);                                                        \
    if (BORDER) {                                                           \
        bool inb_ = ((PX) >= 0.0f) && ((PX) < 1024.0f) &&                   \
                    ((PY) >= 0.0f) && ((PY) < 1024.0f);                     \
        w_ = inb_ ? w_ : 0.0f;                                              \
    }                                                                       \
    float w00_ = C.omx * C.omy, w01_ = C.wx * C.omy;                        \
    float w10_ = C.omx * C.wy,  w11_ = C.wx * C.wy;                         \
    float s0_ = fmaf(w01_, lds[0][C.o01], w00_ * lds[0][C.o00]);            \
    s0_ = fmaf(w10_, lds[0][C.o10], s0_);                                   \
    s0_ = fmaf(w11_, lds[0][C.o11], s0_);                                   \
    A0 = fmaf(s0_, w_, A0);                                                 \
    float s1_ = fmaf(w01_, lds[1][C.o01], w00_ * lds[1][C.o00]);            \
    s1_ = fmaf(w10_, lds[1][C.o10], s1_);                                   \
    s1_ = fmaf(w11_, lds[1][C.o11], s1_);                                   \
    A1 = fmaf(s1_, w_, A1);                                                 \
    float s2_ = fmaf(w01_, lds[2][C.o01], w00_ * lds[2][C.o00]);            \
    s2_ = fmaf(w10_, lds[2][C.o10], s2_);                                   \
    s2_ = fmaf(w11_, lds[2][C.o11], s2_);                                   \
    A2 = fmaf(s2_, w_, A2);                                                 \
    AS += w_;                                                               \
} while (0)

    // tangent advance: contract-off (function-scope pragma), bit-identical
#define ADVSTEP(C, PX, PY, VX, VY) do {                                     \
    float x00_ = lds[3][C.o00], x01_ = lds[3][C.o01];                       \
    float x10_ = lds[3][C.o10], x11_ = lds[3][C.o11];                       \
    float y00_ = lds[4][C.o00], y01_ = lds[4][C.o01];                       \
    float y10_ = lds[4][C.o10], y11_ = lds[4][C.o11];                       \
    float xt_ = x00_ * C.omx + x01_ * C.wx;                                 \
    float xb_ = x10_ * C.omx + x11_ * C.wx;                                 \
    float tfx_ = xt_ * C.omy + xb_ * C.wy;                                  \
    float yt_ = y00_ * C.omx + y01_ * C.wx;                                 \
    float yb_ = y10_ * C.omx + y11_ * C.wx;                                 \
    float tfy_ = yt_ * C.omy + yb_ * C.wy;                                  \
    float vt_ = ((VX) * tfx_) + ((VY) * tfy_);                              \
    if (vt_ < 0.0f) { tfx_ = -tfx_; tfy_ = -tfy_; }                         \
    PX = (PX) + tfx_;  PY = (PY) + tfy_;                                    \
    VX = tfx_;  VY = tfy_;                                                  \
} while (0)

    if (nlive >= 1) {
        MKC(cA0, pxA, pyA);  MKC(cB0, pxB, pyB);
        COLORSTEP(cA0, pxA, pyA, k0, aA0, aA1, aA2, asA);
        COLORSTEP(cB0, pxB, pyB, k0, aB0, aB1, aB2, asB);
        if (nlive >= 2) {
            ADVSTEP(cA0, pxA, pyA, vxA, vyA);
            ADVSTEP(cB0, pxB, pyB, vxB, vyB);
            MKC(cA1, pxA, pyA);  MKC(cB1, pxB, pyB);
            COLORSTEP(cA1, pxA, pyA, k1, aA0, aA1, aA2, asA);
            COLORSTEP(cB1, pxB, pyB, k1, aB0, aB1, aB2, asB);
            if (nlive >= 3) {
                ADVSTEP(cA1, pxA, pyA, vxA, vyA);
                ADVSTEP(cB1, pxB, pyB, vxB, vyB);
                MKC(cA2, pxA, pyA);  MKC(cB2, pxB, pyB);
                COLORSTEP(cA2, pxA, pyA, k2, aA0, aA1, aA2, asA);
                COLORSTEP(cB2, pxB, pyB, k2, aB0, aB1, aB2, asB);
                if (nlive >= 4) {
                    ADVSTEP(cA2, pxA, pyA, vxA, vyA);
                    ADVSTEP(cB2, pxB, pyB, vxB, vyB);
                    MKC(cA3, pxA, pyA);  MKC(cB3, pxB, pyB);
                    COLORSTEP(cA3, pxA, pyA, k3, aA0, aA1, aA2, asA);
                    COLORSTEP(cB3, pxB, pyB, k3, aB0, aB1, aB2, asB);
                }
            }
        }
    }
#undef MKC
#undef COLORSTEP
#undef ADVSTEP

    const int pix = i * Ww + j;
    float xc0 = lds[0][ctr], xc1 = lds[1][ctr], xc2 = lds[2][ctr];
    float denom = (1.0f + asA) + asB;
    float* op = out + (size_t)b * Cc * HWp;
    op[pix]           = ((xc0 + aA0) + aB0) / denom;
    op[pix + HWp]     = ((xc1 + aA1) + aB1) / denom;
    op[pix + 2 * HWp] = ((xc2 + aA2) + aB2) / denom;
}

__global__ __launch_bounds__(512, 8) void flow_smooth_kernel(
    const float* __restrict__ x,
    const float* __restrict__ tg,
    const float* __restrict__ sg,
    float* __restrict__ out)
{
    __shared__ float lds[5][TDY * TSTR];   // 5 x 1344 x 4B = 26.9 KB
    const bool border = (blockIdx.x == 0) || (blockIdx.x == gridDim.x - 1) ||
                        (blockIdx.y == 0) || (blockIdx.y == gridDim.y - 1);
    if (border) run_tile<true >(x, tg, sg, out, lds);
    else        run_tile<false>(x, tg, sg, out, lds);
}

extern "C" void kernel_launch(void* const* d_in, const int* in_sizes, int n_in,
                              void* d_out, int out_size, void* d_ws, size_t ws_size,
                              hipStream_t stream) {
    const float* x = nullptr; const float* tg = nullptr; const float* sg = nullptr;
    for (int t = 0; t < n_in; ++t) {
        if (in_sizes[t] == Bb * Cc * HWp)      x  = (const float*)d_in[t];
        else if (in_sizes[t] == Bb * 2 * HWp)  tg = (const float*)d_in[t];
        else                                   sg = (const float*)d_in[t];
    }
    float* out = (float*)d_out;

    dim3 block(512, 1, 1);
    dim3 grid(Ww / TSX, Hh / TSY, Bb);   // 32 x 64 x 2 = 4096 blocks
    flow_smooth_kernel<<<grid, block, 0, stream>>>(x, tg, sg, out);
}

// Round 8
// 114.623 us; speedup vs baseline: 1.0089x; 1.0083x over previous
//
#include <hip/hip_runtime.h>

// B=2, C=3, H=W=1024, fp32. History: R12 56.1us; R13 float4-record-pack
// regressed; R16 45.3us CHAMPION = 32x8 tile @256thr, TSTR=48 bank-comb
// (conflicts 1.478e7 -> 1.091e7), float2 staging; R17 v2f pack regressed
// (clang scalarized + coupled A/B chains); R18 512-thr/float4 regressed
// (4 blocks/CU: 8-wave barriers + half the independent blocks -> stalls).
// Rule learned: never bundle structural changes; R16 structure is load-bearing.
// R19 = R16 + two additive trims:
//  - HALOY=5 (proven: drift <= 4+4e-6 px => corners span exactly [-5,+5]
//    rows; floor hits i-5 only if drift >= 4.5, impossible). TDY 20->18:
//    -10% staged words/fetch, LDS 19.2->17.3KB (still 8 blocks/CU).
//  - XCD y-band swizzle: 1D grid, swz=(fid%8)*1024+fid/8 (bijective).
//    Each XCD gets a contiguous 32-tile-row band => x-neighbor halo re-reads
//    become same-XCD L2 hits (default round-robin puts x-neighbors on
//    different XCDs; y-neighbors were already same-XCD since 32==0 mod 8).
// March/layout/clamp arithmetic byte-identical to R16 => absmax must remain
// exactly 0.00390625.
constexpr int Bb = 2, Cc = 3, Hh = 1024, Ww = 1024;
constexpr int HWp = Hh * Ww;
constexpr int TSX = 32, TSY = 8;        // tile 32x8, 256 threads
constexpr int HALOX = 6;                // even => float2-aligned staging
constexpr int HALOY = 5;                // exact drift bound
constexpr int TDX = TSX + 2 * HALOX;    // 44
constexpr int TDY = TSY + 2 * HALOY;    // 18
constexpr int TSTR = 48;                // row stride == 16 mod 32: bank comb

struct Corn { int o00, o01, o10, o11; float wx, wy, omx, omy; };

// Interior: pixel-space positions, never clamps (drift bound |dp|<=4+eps px).
__device__ __forceinline__ Corn mkcorn_int(float px, float py, int ox, int oy) {
#pragma clang fp contract(off)
    float fx = px - 0.5f;
    float fy = py - 0.5f;
    float fx0 = floorf(fx), fy0 = floorf(fy);
    Corn c;
    c.wx = fx - fx0;  c.wy = fy - fy0;
    c.omx = 1.0f - c.wx;  c.omy = 1.0f - c.wy;
    int o = ((int)fy0 - oy) * TSTR + ((int)fx0 - ox);
    c.o00 = o;        c.o01 = o + 1;          // read2-mergeable pairs
    c.o10 = o + TSTR; c.o11 = o + TSTR + 1;
    return c;
}

// Border: full clamp logic, arithmetic identical to R12/R16.
__device__ __forceinline__ Corn mkcorn_bor(float px, float py, int ox, int oy) {
#pragma clang fp contract(off)
    float fx = px - 0.5f;
    float fy = py - 0.5f;
    float fx0 = floorf(fx), fy0 = floorf(fy);
    Corn c;
    c.wx = fx - fx0;  c.wy = fy - fy0;
    c.omx = 1.0f - c.wx;  c.omy = 1.0f - c.wy;
    int x0 = (int)fx0, y0 = (int)fy0;
    int x0i = min(max(x0, 0), Ww - 1);
    int x1i = min(x0i + 1, Ww - 1);
    int y0i = min(max(y0, 0), Hh - 1);
    int y1i = min(y0i + 1, Hh - 1);
    int lx0 = x0i - ox, lx1 = x1i - ox;
    int ly0 = y0i - oy, ly1 = y1i - oy;
    c.o00 = ly0 * TSTR + lx0;  c.o01 = ly0 * TSTR + lx1;
    c.o10 = ly1 * TSTR + lx0;  c.o11 = ly1 * TSTR + lx1;
    return c;
}

template <bool BORDER>
__device__ __forceinline__ void run_tile(
    int bx, int by, int b,
    const float* __restrict__ x, const float* __restrict__ tg,
    const float* __restrict__ sg, float* __restrict__ out,
    float (&lds)[5][TDY * TSTR])
{
#pragma clang fp contract(off)
    const int tx0 = bx * TSX, ty0 = by * TSY;
    const int tid = threadIdx.x;          // 0..255

    const float* xp  = x  + (size_t)b * Cc * HWp;
    const float* txp = tg + (size_t)b * 2 * HWp;
    const float* planes[5] = { xp, xp + HWp, xp + 2 * HWp, txp, txp + HWp };
    const int ox = tx0 - HALOX, oy = ty0 - HALOY;

    // ---- uniform per-block kernel weights (overlap staging latency)
    float sig = sg[b];
    float half_width = 2.0f * sig;
    float two_sigma2 = (2.0f * sig) * sig;
    const float stepf = (float)(1.0 / 0.3333);
    float kv[4];
#pragma unroll
    for (int it = 0; it < 4; ++it) {
        float r = ((float)it + 1.0f) * stepf;
        float k = expf(-(r * r) / two_sigma2);
        kv[it] = (r < half_width) ? k : 0.0f;
    }
    const float k0 = kv[0], k1 = kv[1], k2 = kv[2], k3 = kv[3];
    // ks-nonzero is a prefix (exp never 0; r<half_width monotone shut-off).
    const int nlive = __builtin_amdgcn_readfirstlane(
        (k0 != 0.0f) + (k1 != 0.0f) + (k2 != 0.0f) + (k3 != 0.0f));

    // ---- stage 18x44 x 5 planes into LDS
    if (!BORDER) {
        // interior: ox is even (tx0 = 32k, HALOX = 6) => float2 aligned
        for (int e = tid; e < TDY * (TDX / 2); e += 256) {
            int r = e / (TDX / 2);
            int c2 = e - r * (TDX / 2);
            int g = (oy + r) * Ww + ox + 2 * c2;
            int d = r * TSTR + 2 * c2;
#pragma unroll
            for (int pl = 0; pl < 5; ++pl) {
                float2 v = *reinterpret_cast<const float2*>(planes[pl] + g);
                *reinterpret_cast<float2*>(&lds[pl][d]) = v;
            }
        }
    } else {
        for (int e = tid; e < TDY * TDX; e += 256) {
            int r = e / TDX, cc = e - r * TDX;
            int gy = min(max(oy + r, 0), Hh - 1);
            int gx = min(max(ox + cc, 0), Ww - 1);
            int g = gy * Ww + gx;
#pragma unroll
            for (int pl = 0; pl < 5; ++pl)
                lds[pl][r * TSTR + cc] = planes[pl][g];
        }
    }
    __syncthreads();

    // ---- per-pixel march, positions in PIXEL units (exact x1024 rescale)
    const int lx = tid & (TSX - 1), ly = tid >> 5;   // 32x8
    const int j = tx0 + lx, i = ty0 + ly;
    const int ctr = (HALOY + ly) * TSTR + (HALOX + lx);

    const float psx = (float)j + 0.5f;
    const float psy = (float)i + 0.5f;

    const float v0x = lds[3][ctr];
    const float v0y = lds[4][ctr];

    // two independent chains: A = +v0, B = -v0 (manually interleaved)
    float pxA = psx + v0x, pyA = psy + v0y, vxA = v0x, vyA = v0y;
    float pxB = psx - v0x, pyB = psy - v0y, vxB = -v0x, vyB = -v0y;
    float aA0 = 0.f, aA1 = 0.f, aA2 = 0.f, asA = 0.f;
    float aB0 = 0.f, aB1 = 0.f, aB2 = 0.f, asB = 0.f;

#define MKC(C, PX, PY)                                                      \
    Corn C = BORDER ? mkcorn_bor(PX, PY, ox, oy)                            \
                    : mkcorn_int(PX, PY, ox, oy)

#define COLORSTEP(C, PX, PY, KW, A0, A1, A2, AS) do {                       \
    float w_ = (KW);                                                        \
    if (BORDER) {                                                           \
        bool inb_ = ((PX) >= 0.0f) && ((PX) < 1024.0f) &&                   \
                    ((PY) >= 0.0f) && ((PY) < 1024.0f);                     \
        w_ = inb_ ? w_ : 0.0f;                                              \
    }                                                                       \
    float w00_ = C.omx * C.omy, w01_ = C.wx * C.omy;                        \
    float w10_ = C.omx * C.wy,  w11_ = C.wx * C.wy;                         \
    float s0_ = fmaf(w01_, lds[0][C.o01], w00_ * lds[0][C.o00]);            \
    s0_ = fmaf(w10_, lds[0][C.o10], s0_);                                   \
    s0_ = fmaf(w11_, lds[0][C.o11], s0_);                                   \
    A0 = fmaf(s0_, w_, A0);                                                 \
    float s1_ = fmaf(w01_, lds[1][C.o01], w00_ * lds[1][C.o00]);            \
    s1_ = fmaf(w10_, lds[1][C.o10], s1_);                                   \
    s1_ = fmaf(w11_, lds[1][C.o11], s1_);                                   \
    A1 = fmaf(s1_, w_, A1);                                                 \
    float s2_ = fmaf(w01_, lds[2][C.o01], w00_ * lds[2][C.o00]);            \
    s2_ = fmaf(w10_, lds[2][C.o10], s2_);                                   \
    s2_ = fmaf(w11_, lds[2][C.o11], s2_);                                   \
    A2 = fmaf(s2_, w_, A2);                                                 \
    AS += w_;                                                               \
} while (0)

    // tangent advance: contract-off (function-scope pragma), bit-identical
#define ADVSTEP(C, PX, PY, VX, VY) do {                                     \
    float x00_ = lds[3][C.o00], x01_ = lds[3][C.o01];                       \
    float x10_ = lds[3][C.o10], x11_ = lds[3][C.o11];                       \
    float y00_ = lds[4][C.o00], y01_ = lds[4][C.o01];                       \
    float y10_ = lds[4][C.o10], y11_ = lds[4][C.o11];                       \
    float xt_ = x00_ * C.omx + x01_ * C.wx;                                 \
    float xb_ = x10_ * C.omx + x11_ * C.wx;                                 \
    float tfx_ = xt_ * C.omy + xb_ * C.wy;                                  \
    float yt_ = y00_ * C.omx + y01_ * C.wx;                                 \
    float yb_ = y10_ * C.omx + y11_ * C.wx;                                 \
    float tfy_ = yt_ * C.omy + yb_ * C.wy;                                  \
    float vt_ = ((VX) * tfx_) + ((VY) * tfy_);                              \
    if (vt_ < 0.0f) { tfx_ = -tfx_; tfy_ = -tfy_; }                         \
    PX = (PX) + tfx_;  PY = (PY) + tfy_;                                    \
    VX = tfx_;  VY = tfy_;                                                  \
} while (0)

    if (nlive >= 1) {
        MKC(cA0, pxA, pyA);  MKC(cB0, pxB, pyB);
        COLORSTEP(cA0, pxA, pyA, k0, aA0, aA1, aA2, asA);
        COLORSTEP(cB0, pxB, pyB, k0, aB0, aB1, aB2, asB);
        if (nlive >= 2) {
            ADVSTEP(cA0, pxA, pyA, vxA, vyA);
            ADVSTEP(cB0, pxB, pyB, vxB, vyB);
            MKC(cA1, pxA, pyA);  MKC(cB1, pxB, pyB);
            COLORSTEP(cA1, pxA, pyA, k1, aA0, aA1, aA2, asA);
            COLORSTEP(cB1, pxB, pyB, k1, aB0, aB1, aB2, asB);
            if (nlive >= 3) {
                ADVSTEP(cA1, pxA, pyA, vxA, vyA);
                ADVSTEP(cB1, pxB, pyB, vxB, vyB);
                MKC(cA2, pxA, pyA);  MKC(cB2, pxB, pyB);
                COLORSTEP(cA2, pxA, pyA, k2, aA0, aA1, aA2, asA);
                COLORSTEP(cB2, pxB, pyB, k2, aB0, aB1, aB2, asB);
                if (nlive >= 4) {
                    ADVSTEP(cA2, pxA, pyA, vxA, vyA);
                    ADVSTEP(cB2, pxB, pyB, vxB, vyB);
                    MKC(cA3, pxA, pyA);  MKC(cB3, pxB, pyB);
                    COLORSTEP(cA3, pxA, pyA, k3, aA0, aA1, aA2, asA);
                    COLORSTEP(cB3, pxB, pyB, k3, aB0, aB1, aB2, asB);
                }
            }
        }
    }
#undef MKC
#undef COLORSTEP
#undef ADVSTEP

    const int pix = i * Ww + j;
    float xc0 = lds[0][ctr], xc1 = lds[1][ctr], xc2 = lds[2][ctr];
    float denom = (1.0f + asA) + asB;
    float* op = out + (size_t)b * Cc * HWp;
    op[pix]           = ((xc0 + aA0) + aB0) / denom;
    op[pix + HWp]     = ((xc1 + aA1) + aB1) / denom;
    op[pix + 2 * HWp] = ((xc2 + aA2) + aB2) / denom;
}

__global__ __launch_bounds__(256, 8) void flow_smooth_kernel(
    const float* __restrict__ x,
    const float* __restrict__ tg,
    const float* __restrict__ sg,
    float* __restrict__ out)
{
    __shared__ float lds[5][TDY * TSTR];   // 5 x 864 x 4B = 17.3 KB

    // XCD y-band swizzle (bijective: 8192 = 8 x 1024). Assuming round-robin
    // fid%8 -> XCD, XCD k runs tiles [k*1024,(k+1)*1024) = one contiguous
    // 32-tile-row band, row-major => x/y-neighbor halos are L2-local.
    // Pure perf heuristic: any bijection is correctness-safe.
    const int fid = blockIdx.x;
    const int swz = (fid & 7) * 1024 + (fid >> 3);
    const int b  = swz >> 12;            // / 4096
    const int rem = swz & 4095;
    const int by = rem >> 5;             // / 32
    const int bx = rem & 31;

    const bool border = (bx == 0) || (bx == 31) || (by == 0) || (by == 127);
    if (border) run_tile<true >(bx, by, b, x, tg, sg, out, lds);
    else        run_tile<false>(bx, by, b, x, tg, sg, out, lds);
}

extern "C" void kernel_launch(void* const* d_in, const int* in_sizes, int n_in,
                              void* d_out, int out_size, void* d_ws, size_t ws_size,
                              hipStream_t stream) {
    const float* x = nullptr; const float* tg = nullptr; const float* sg = nullptr;
    for (int t = 0; t < n_in; ++t) {
        if (in_sizes[t] == Bb * Cc * HWp)      x  = (const float*)d_in[t];
        else if (in_sizes[t] == Bb * 2 * HWp)  tg = (const float*)d_in[t];
        else                                   sg = (const float*)d_in[t];
    }
    float* out = (float*)d_out;

    dim3 block(256, 1, 1);
    dim3 grid(8192, 1, 1);   // (Ww/TSX) x (Hh/TSY) x Bb = 32*128*2, flattened
    flow_smooth_kernel<<<grid, block, 0, stream>>>(x, tg, sg, out);
}

// Round 9
// 113.979 us; speedup vs baseline: 1.0146x; 1.0056x over previous
//
#include <hip/hip_runtime.h>

// B=2, C=3, H=W=1024, fp32. History: R16 45.3us (32x8 tile @256thr, TSTR=48
// bank-comb, conflicts 1.478e7->1.09e7); R17 v2f pack regressed (scalarized +
// coupled A/B chains); R18 512-thr float4 staging regressed (4 blocks/CU
// structure loss, NOT the float4 staging itself); R19 44.2us = R16 + HALOY=5
// + XCD y-band swizzle (FETCH 60.5->21.2MB, HBM 13%).
// Budget @44.2us: LDS path ~65% (42k cy/CU iid-drift conflicts -- white-noise
// tangent => irreducible by layout), VALU ~61%, staging instrs the largest
// removable term.
// R20 = R19 + float4 staging ONLY (the R18 win without the R18 structure
// change): HALOX=8 => ox == 0 mod 4, TDX=48=TSTR; interior staging = 216
// lanes x 5 x {global_load_dwordx4 -> ds_write_b128}, one shared address +
// 5 plane-offset immediates (plane stride 3456B < 64KB ds-offset imm).
// LDS size unchanged 17.3KB -> 8 blocks/CU. March/clamp arithmetic
// byte-identical => absmax must remain exactly 0.00390625.
constexpr int Bb = 2, Cc = 3, Hh = 1024, Ww = 1024;
constexpr int HWp = Hh * Ww;
constexpr int TSX = 32, TSY = 8;        // tile 32x8, 256 threads
constexpr int HALOX = 8;                // 0 mod 4 => float4-aligned staging
constexpr int HALOY = 5;                // exact drift bound (<= 4+eps px)
constexpr int TDX = TSX + 2 * HALOX;    // 48 == TSTR
constexpr int TDY = TSY + 2 * HALOY;    // 18
constexpr int TSTR = 48;                // row stride == 16 mod 32: bank comb

struct Corn { int o00, o01, o10, o11; float wx, wy, omx, omy; };

// Interior: pixel-space positions, never clamps (drift bound |dp|<=4+eps px).
__device__ __forceinline__ Corn mkcorn_int(float px, float py, int ox, int oy) {
#pragma clang fp contract(off)
    float fx = px - 0.5f;
    float fy = py - 0.5f;
    float fx0 = floorf(fx), fy0 = floorf(fy);
    Corn c;
    c.wx = fx - fx0;  c.wy = fy - fy0;
    c.omx = 1.0f - c.wx;  c.omy = 1.0f - c.wy;
    int o = ((int)fy0 - oy) * TSTR + ((int)fx0 - ox);
    c.o00 = o;        c.o01 = o + 1;          // read2-mergeable pairs
    c.o10 = o + TSTR; c.o11 = o + TSTR + 1;
    return c;
}

// Border: full clamp logic, arithmetic identical to R12/R16.
__device__ __forceinline__ Corn mkcorn_bor(float px, float py, int ox, int oy) {
#pragma clang fp contract(off)
    float fx = px - 0.5f;
    float fy = py - 0.5f;
    float fx0 = floorf(fx), fy0 = floorf(fy);
    Corn c;
    c.wx = fx - fx0;  c.wy = fy - fy0;
    c.omx = 1.0f - c.wx;  c.omy = 1.0f - c.wy;
    int x0 = (int)fx0, y0 = (int)fy0;
    int x0i = min(max(x0, 0), Ww - 1);
    int x1i = min(x0i + 1, Ww - 1);
    int y0i = min(max(y0, 0), Hh - 1);
    int y1i = min(y0i + 1, Hh - 1);
    int lx0 = x0i - ox, lx1 = x1i - ox;
    int ly0 = y0i - oy, ly1 = y1i - oy;
    c.o00 = ly0 * TSTR + lx0;  c.o01 = ly0 * TSTR + lx1;
    c.o10 = ly1 * TSTR + lx0;  c.o11 = ly1 * TSTR + lx1;
    return c;
}

template <bool BORDER>
__device__ __forceinline__ void run_tile(
    int bx, int by, int b,
    const float* __restrict__ x, const float* __restrict__ tg,
    const float* __restrict__ sg, float* __restrict__ out,
    float (&lds)[5][TDY * TSTR])
{
#pragma clang fp contract(off)
    const int tx0 = bx * TSX, ty0 = by * TSY;
    const int tid = threadIdx.x;          // 0..255

    const float* xp  = x  + (size_t)b * Cc * HWp;
    const float* txp = tg + (size_t)b * 2 * HWp;
    const float* planes[5] = { xp, xp + HWp, xp + 2 * HWp, txp, txp + HWp };
    const int ox = tx0 - HALOX, oy = ty0 - HALOY;   // ox == 0 mod 4

    // ---- uniform per-block kernel weights (overlap staging latency)
    float sig = sg[b];
    float half_width = 2.0f * sig;
    float two_sigma2 = (2.0f * sig) * sig;
    const float stepf = (float)(1.0 / 0.3333);
    float kv[4];
#pragma unroll
    for (int it = 0; it < 4; ++it) {
        float r = ((float)it + 1.0f) * stepf;
        float k = expf(-(r * r) / two_sigma2);
        kv[it] = (r < half_width) ? k : 0.0f;
    }
    const float k0 = kv[0], k1 = kv[1], k2 = kv[2], k3 = kv[3];
    // ks-nonzero is a prefix (exp never 0; r<half_width monotone shut-off).
    const int nlive = __builtin_amdgcn_readfirstlane(
        (k0 != 0.0f) + (k1 != 0.0f) + (k2 != 0.0f) + (k3 != 0.0f));

    // ---- stage 18x48 x 5 planes into LDS
    if (!BORDER) {
        // interior: ox == 0 mod 4 => float4 loads + b128 LDS writes.
        // 18 rows x 12 vec4 = 216 slots; one (r,c4) address shared by all
        // 5 planes (LDS plane stride 3456B fits the 16-bit ds offset).
        const int e = tid;
        if (e < TDY * (TDX / 4)) {
            int r  = e / (TDX / 4);
            int c4 = e - r * (TDX / 4);
            int g = (oy + r) * Ww + ox + 4 * c4;
            int d = r * TSTR + 4 * c4;
#pragma unroll
            for (int pl = 0; pl < 5; ++pl) {
                float4 v = *reinterpret_cast<const float4*>(planes[pl] + g);
                *reinterpret_cast<float4*>(&lds[pl][d]) = v;
            }
        }
    } else {
        for (int e = tid; e < TDY * TDX; e += 256) {
            int r = e / TDX, cc = e - r * TDX;
            int gy = min(max(oy + r, 0), Hh - 1);
            int gx = min(max(ox + cc, 0), Ww - 1);
            int g = gy * Ww + gx;
#pragma unroll
            for (int pl = 0; pl < 5; ++pl)
                lds[pl][r * TSTR + cc] = planes[pl][g];
        }
    }
    __syncthreads();

    // ---- per-pixel march, positions in PIXEL units (exact x1024 rescale)
    const int lx = tid & (TSX - 1), ly = tid >> 5;   // 32x8
    const int j = tx0 + lx, i = ty0 + ly;
    const int ctr = (HALOY + ly) * TSTR + (HALOX + lx);

    const float psx = (float)j + 0.5f;
    const float psy = (float)i + 0.5f;

    const float v0x = lds[3][ctr];
    const float v0y = lds[4][ctr];

    // two independent chains: A = +v0, B = -v0 (manually interleaved)
    float pxA = psx + v0x, pyA = psy + v0y, vxA = v0x, vyA = v0y;
    float pxB = psx - v0x, pyB = psy - v0y, vxB = -v0x, vyB = -v0y;
    float aA0 = 0.f, aA1 = 0.f, aA2 = 0.f, asA = 0.f;
    float aB0 = 0.f, aB1 = 0.f, aB2 = 0.f, asB = 0.f;

#define MKC(C, PX, PY)                                                      \
    Corn C = BORDER ? mkcorn_bor(PX, PY, ox, oy)                            \
                    : mkcorn_int(PX, PY, ox, oy)

#define COLORSTEP(C, PX, PY, KW, A0, A1, A2, AS) do {                       \
    float w_ = (KW);                                                        \
    if (BORDER) {                                                           \
        bool inb_ = ((PX) >= 0.0f) && ((PX) < 1024.0f) &&                   \
                    ((PY) >= 0.0f) && ((PY) < 1024.0f);                     \
        w_ = inb_ ? w_ : 0.0f;                                              \
    }                                                                       \
    float w00_ = C.omx * C.omy, w01_ = C.wx * C.omy;                        \
    float w10_ = C.omx * C.wy,  w11_ = C.wx * C.wy;                         \
    float s0_ = fmaf(w01_, lds[0][C.o01], w00_ * lds[0][C.o00]);            \
    s0_ = fmaf(w10_, lds[0][C.o10], s0_);                                   \
    s0_ = fmaf(w11_, lds[0][C.o11], s0_);                                   \
    A0 = fmaf(s0_, w_, A0);                                                 \
    float s1_ = fmaf(w01_, lds[1][C.o01], w00_ * lds[1][C.o00]);            \
    s1_ = fmaf(w10_, lds[1][C.o10], s1_);                                   \
    s1_ = fmaf(w11_, lds[1][C.o11], s1_);                                   \
    A1 = fmaf(s1_, w_, A1);                                                 \
    float s2_ = fmaf(w01_, lds[2][C.o01], w00_ * lds[2][C.o00]);            \
    s2_ = fmaf(w10_, lds[2][C.o10], s2_);                                   \
    s2_ = fmaf(w11_, lds[2][C.o11], s2_);                                   \
    A2 = fmaf(s2_, w_, A2);                                                 \
    AS += w_;                                                               \
} while (0)

    // tangent advance: contract-off (function-scope pragma), bit-identical
#define ADVSTEP(C, PX, PY, VX, VY) do {                                     \
    float x00_ = lds[3][C.o00], x01_ = lds[3][C.o01];                       \
    float x10_ = lds[3][C.o10], x11_ = lds[3][C.o11];                       \
    float y00_ = lds[4][C.o00], y01_ = lds[4][C.o01];                       \
    float y10_ = lds[4][C.o10], y11_ = lds[4][C.o11];                       \
    float xt_ = x00_ * C.omx + x01_ * C.wx;                                 \
    float xb_ = x10_ * C.omx + x11_ * C.wx;                                 \
    float tfx_ = xt_ * C.omy + xb_ * C.wy;                                  \
    float yt_ = y00_ * C.omx + y01_ * C.wx;                                 \
    float yb_ = y10_ * C.omx + y11_ * C.wx;                                 \
    float tfy_ = yt_ * C.omy + yb_ * C.wy;                                  \
    float vt_ = ((VX) * tfx_) + ((VY) * tfy_);                              \
    if (vt_ < 0.0f) { tfx_ = -tfx_; tfy_ = -tfy_; }                         \
    PX = (PX) + tfx_;  PY = (PY) + tfy_;                                    \
    VX = tfx_;  VY = tfy_;                                                  \
} while (0)

    if (nlive >= 1) {
        MKC(cA0, pxA, pyA);  MKC(cB0, pxB, pyB);
        COLORSTEP(cA0, pxA, pyA, k0, aA0, aA1, aA2, asA);
        COLORSTEP(cB0, pxB, pyB, k0, aB0, aB1, aB2, asB);
        if (nlive >= 2) {
            ADVSTEP(cA0, pxA, pyA, vxA, vyA);
            ADVSTEP(cB0, pxB, pyB, vxB, vyB);
            MKC(cA1, pxA, pyA);  MKC(cB1, pxB, pyB);
            COLORSTEP(cA1, pxA, pyA, k1, aA0, aA1, aA2, asA);
            COLORSTEP(cB1, pxB, pyB, k1, aB0, aB1, aB2, asB);
            if (nlive >= 3) {
                ADVSTEP(cA1, pxA, pyA, vxA, vyA);
                ADVSTEP(cB1, pxB, pyB, vxB, vyB);
                MKC(cA2, pxA, pyA);  MKC(cB2, pxB, pyB);
                COLORSTEP(cA2, pxA, pyA, k2, aA0, aA1, aA2, asA);
                COLORSTEP(cB2, pxB, pyB, k2, aB0, aB1, aB2, asB);
                if (nlive >= 4) {
                    ADVSTEP(cA2, pxA, pyA, vxA, vyA);
                    ADVSTEP(cB2, pxB, pyB, vxB, vyB);
                    MKC(cA3, pxA, pyA);  MKC(cB3, pxB, pyB);
                    COLORSTEP(cA3, pxA, pyA, k3, aA0, aA1, aA2, asA);
                    COLORSTEP(cB3, pxB, pyB, k3, aB0, aB1, aB2, asB);
                }
            }
        }
    }
#undef MKC
#undef COLORSTEP
#undef ADVSTEP

    const int pix = i * Ww + j;
    float xc0 = lds[0][ctr], xc1 = lds[1][ctr], xc2 = lds[2][ctr];
    float denom = (1.0f + asA) + asB;
    float* op = out + (size_t)b * Cc * HWp;
    op[pix]           = ((xc0 + aA0) + aB0) / denom;
    op[pix + HWp]     = ((xc1 + aA1) + aB1) / denom;
    op[pix + 2 * HWp] = ((xc2 + aA2) + aB2) / denom;
}

__global__ __launch_bounds__(256, 8) void flow_smooth_kernel(
    const float* __restrict__ x,
    const float* __restrict__ tg,
    const float* __restrict__ sg,
    float* __restrict__ out)
{
    __shared__ float lds[5][TDY * TSTR];   // 5 x 864 x 4B = 17.3 KB

    // XCD y-band swizzle (bijective: 8192 = 8 x 1024). XCD k gets one
    // contiguous 32-tile-row band, row-major => x/y-neighbor halo re-reads
    // are L2-local (R19: FETCH 60.5 -> 21.2 MB).
    const int fid = blockIdx.x;
    const int swz = (fid & 7) * 1024 + (fid >> 3);
    const int b  = swz >> 12;            // / 4096
    const int rem = swz & 4095;
    const int by = rem >> 5;             // / 32
    const int bx = rem & 31;

    const bool border = (bx == 0) || (bx == 31) || (by == 0) || (by == 127);
    if (border) run_tile<true >(bx, by, b, x, tg, sg, out, lds);
    else        run_tile<false>(bx, by, b, x, tg, sg, out, lds);
}

extern "C" void kernel_launch(void* const* d_in, const int* in_sizes, int n_in,
                              void* d_out, int out_size, void* d_ws, size_t ws_size,
                              hipStream_t stream) {
    const float* x = nullptr; const float* tg = nullptr; const float* sg = nullptr;
    for (int t = 0; t < n_in; ++t) {
        if (in_sizes[t] == Bb * Cc * HWp)      x  = (const float*)d_in[t];
        else if (in_sizes[t] == Bb * 2 * HWp)  tg = (const float*)d_in[t];
        else                                   sg = (const float*)d_in[t];
    }
    float* out = (float*)d_out;

    dim3 block(256, 1, 1);
    dim3 grid(8192, 1, 1);   // (Ww/TSX) x (Hh/TSY) x Bb = 32*128*2, flattened
    flow_smooth_kernel<<<grid, block, 0, stream>>>(x, tg, sg, out);
}